// Round 6
// baseline (281.019 us; speedup 1.0000x reference)
//
#include <hip/hip_runtime.h>
#include <stdint.h>

#define DEV __device__ __forceinline__

typedef __attribute__((ext_vector_type(8))) __bf16 bf16x8;
typedef __attribute__((ext_vector_type(4))) float floatx4;

DEV unsigned int f2bf(float f) {
  union { float f; unsigned int i; } x; x.f = f;
  unsigned int r = x.i + 0x7FFFu + ((x.i >> 16) & 1u);
  return r >> 16;
}
DEV void gl2lds16(const unsigned short* g, unsigned short* l) {
  __builtin_amdgcn_global_load_lds(
      (const __attribute__((address_space(1))) unsigned int*)g,
      (__attribute__((address_space(3))) unsigned int*)l, 16, 0, 0);
}
DEV floatx4 zero4() { floatx4 z; z[0]=0.f; z[1]=0.f; z[2]=0.f; z[3]=0.f; return z; }

// ---- merged prep: [0,1024) weight transposes; [1024,17408) e f32->bf16;
//      [17408,21504) rmsnorm; [21504,21756) head-row copy ---------------------
__global__ void cca_prep_k(const float* __restrict__ W0, const float* __restrict__ W1,
                           const float* __restrict__ W2, const float* __restrict__ W3,
                           unsigned short* __restrict__ D0, unsigned short* __restrict__ D1,
                           unsigned short* __restrict__ D2, unsigned short* __restrict__ D3,
                           const float* __restrict__ e, unsigned short* __restrict__ eb,
                           const float* __restrict__ h, const float* __restrict__ g,
                           unsigned short* __restrict__ hn, float* __restrict__ out) {
  __shared__ float tile[64][65];
  int blk = blockIdx.x;
  int t = threadIdx.x;
  if (blk < 1024) {                       // weight transpose, 64x64 tile
    const float* W; unsigned short* Wt;
    switch (blk >> 8) {
      case 0: W = W0; Wt = D0; break;
      case 1: W = W1; Wt = D1; break;
      case 2: W = W2; Wt = D2; break;
      default: W = W3; Wt = D3; break;
    }
    int k0 = (blk & 15) * 64, n0 = ((blk >> 4) & 15) * 64;
    int c = t & 63, r4 = t >> 6;
#pragma unroll
    for (int it = 0; it < 16; ++it) {
      int r = it * 4 + r4;
      tile[r][c] = W[(size_t)(k0 + r) * 1024 + n0 + c];
    }
    __syncthreads();
#pragma unroll
    for (int it = 0; it < 16; ++it) {
      int r = it * 4 + r4;
      Wt[(size_t)(n0 + r) * 1024 + k0 + c] = (unsigned short)f2bf(tile[c][r]);
    }
    return;
  }
  if (blk < 17408) {                      // e f32 -> bf16, 1024 elems/block
    int i = (blk - 1024) * 256 + t;
    float4 v = ((const float4*)e)[i];
    uint2 o;
    o.x = f2bf(v.x) | (f2bf(v.y) << 16);
    o.y = f2bf(v.z) | (f2bf(v.w) << 16);
    ((uint2*)eb)[i] = o;
    return;
  }
  if (blk < 21504) {                      // rmsnorm row
    int row = blk - 17408;                // 0..4095
    int b = row >> 10, p = row & 1023;
    unsigned short* dst = hn + (size_t)row * 1024;
    if (p >= 961) {
      uint2 z; z.x = 0u; z.y = 0u;
      ((uint2*)dst)[t] = z;
      return;
    }
    const float* src = h + ((size_t)(b << 10) + p + 63) * 1024;
    float4 v = ((const float4*)src)[t];
    float ss = v.x*v.x + v.y*v.y + v.z*v.z + v.w*v.w;
#pragma unroll
    for (int m = 32; m > 0; m >>= 1) ss += __shfl_down(ss, m);
    __shared__ float wsum[4];
    int lane = t & 63, wv = t >> 6;
    if (lane == 0) wsum[wv] = ss;
    __syncthreads();
    float tot = wsum[0] + wsum[1] + wsum[2] + wsum[3];
    float r = rsqrtf(tot * (1.0f / 1024.0f) + 1e-8f);
    float4 gv = ((const float4*)g)[t];
    uint2 outp;
    outp.x = f2bf(v.x * gv.x * r) | (f2bf(v.y * gv.y * r) << 16);
    outp.y = f2bf(v.z * gv.z * r) | (f2bf(v.w * gv.w * r) << 16);
    ((uint2*)dst)[t] = outp;
    return;
  }
  {                                        // head copy, one float4/thread
    int idx = (blk - 21504) * 256 + t;
    const int n4 = 4 * 63 * 1024 / 4;      // 64512
    if (idx < n4) {
      int e4 = idx * 4;
      int b = e4 / (63 * 1024);
      int r = e4 - b * (63 * 1024);
      size_t off = (size_t)b * 1024 * 1024 + (size_t)r;
      *(float4*)(out + off) = *(const float4*)(h + off);
    }
  }
}

// ---- merged QKV GEMM, n-fast block order, fused V-transpose epilogue -------
// blocks [0,2048): KV. mblk=blk>>4, n=blk&15. n<8 -> K half (store KVb cols
//   [0,1024)); n>=8 -> V half, stored transposed+swizzled into KVb's V-half
//   region: VT(chunk,hh,d,key) at KVb[chunk*524288 + (hh*16+(idx>>10))*2048
//   + 1024 + (idx&1023)], idx = d*256 + ((u^(d&7))<<3) + (key&7), u=key>>3.
// blocks [2048,2304): Q proj (M=4096,N=1024) -> Qb.
__launch_bounds__(256, 2)
__global__ void cca_gemmQKV_k(const unsigned short* __restrict__ eb,
                              const unsigned short* __restrict__ WkvT,
                              const float* __restrict__ bk,
                              const float* __restrict__ bv,
                              unsigned short* __restrict__ KVb,
                              const unsigned short* __restrict__ hn,
                              const unsigned short* __restrict__ WqT,
                              const float* __restrict__ bq,
                              unsigned short* __restrict__ Qb) {
  __shared__ unsigned short Ash[128 * 64];
  __shared__ unsigned short Bsh[128 * 64];
  int blk = blockIdx.x;
  const unsigned short *A, *Bt;
  int tM, tN;
  bool isQ = (blk >= 2048), isV = false;
  if (!isQ) {
    int mblk = blk >> 4, n = blk & 15;
    tM = mblk * 128; tN = n * 128; isV = (n >= 8);
    A = eb; Bt = WkvT;
  } else {
    int q = blk - 2048;
    tM = (q >> 3) * 128; tN = (q & 7) * 128;
    A = hn; Bt = WqT;
  }
  int t = threadIdx.x, lane = t & 63, wv = t >> 6;
  int wm = wv >> 1, wn = wv & 1;
  int l15 = lane & 15, quad = lane >> 4;
  int arow = lane >> 3, achk = lane & 7;     // staging: 8 lanes / 128B row
  int gchk = achk ^ arow;                    // 3-bit XOR swizzled source unit
  floatx4 acc[4][4];
#pragma unroll
  for (int i = 0; i < 4; ++i)
#pragma unroll
    for (int j = 0; j < 4; ++j) acc[i][j] = zero4();

  for (int k0 = 0; k0 < 1024; k0 += 64) {
    __syncthreads();
#pragma unroll
    for (int ii = 0; ii < 4; ++ii) {
      int seg = ii * 4 + wv;                 // 0..15, 8 rows each
      int row = seg * 8 + arow;
      gl2lds16(A + (size_t)(tM + row) * 1024 + k0 + gchk * 8, Ash + seg * 512);
      gl2lds16(Bt + (size_t)(tN + row) * 1024 + k0 + gchk * 8, Bsh + seg * 512);
    }
    __syncthreads();
#pragma unroll
    for (int hseg = 0; hseg < 2; ++hseg) {
      int u = (hseg << 2) | quad;
      bf16x8 af[4], bfv[4];
#pragma unroll
      for (int mt = 0; mt < 4; ++mt) {
        int r = wm * 64 + mt * 16 + l15;
        af[mt] = *(const bf16x8*)&Ash[r * 64 + ((u ^ (l15 & 7)) << 3)];
      }
#pragma unroll
      for (int nt = 0; nt < 4; ++nt) {
        int r = wn * 64 + nt * 16 + l15;
        bfv[nt] = *(const bf16x8*)&Bsh[r * 64 + ((u ^ (l15 & 7)) << 3)];
      }
#pragma unroll
      for (int mt = 0; mt < 4; ++mt)
#pragma unroll
        for (int nt = 0; nt < 4; ++nt)
          acc[mt][nt] = __builtin_amdgcn_mfma_f32_16x16x32_bf16(af[mt], bfv[nt], acc[mt][nt], 0, 0, 0);
    }
  }

  if (isV) {
    // V half: write transposed+swizzled VT into KVb's V region
    int chunk = tM >> 8;                    // b*16+c
    int keybase = tM & 255;                 // 0 or 128
    unsigned short* vdst = KVb + (size_t)chunk * 524288 + 1024;
#pragma unroll
    for (int mt = 0; mt < 4; ++mt) {
      int key = keybase + wm * 64 + mt * 16 + quad * 4;
      int u = key >> 3, j0 = key & 7;       // j0 in {0,4}
#pragma unroll
      for (int nt = 0; nt < 4; ++nt) {
        int dcol = (tN - 1024) + wn * 64 + nt * 16 + l15;  // 0..1023
        int hh = dcol >> 6, d = dcol & 63;
        float bs = bv[dcol];
        uint2 o;
        o.x = f2bf(acc[mt][nt][0] + bs) | (f2bf(acc[mt][nt][1] + bs) << 16);
        o.y = f2bf(acc[mt][nt][2] + bs) | (f2bf(acc[mt][nt][3] + bs) << 16);
        int idx = d * 256 + ((u ^ (d & 7)) << 3) + j0;
        *(uint2*)(vdst + (size_t)(hh * 16 + (idx >> 10)) * 2048 + (idx & 1023)) = o;
      }
    }
    return;
  }
#pragma unroll
  for (int mt = 0; mt < 4; ++mt) {
    int mrow = tM + wm * 64 + mt * 16 + quad * 4;
#pragma unroll
    for (int nt = 0; nt < 4; ++nt) {
      int ncol = tN + wn * 64 + nt * 16 + l15;
      float bs = isQ ? bq[ncol] : bk[ncol];
#pragma unroll
      for (int r = 0; r < 4; ++r) {
        int m = mrow + r;
        if (isQ) Qb[(size_t)m * 1024 + ncol] = (unsigned short)f2bf(acc[mt][nt][r] + bs);
        else     KVb[(size_t)m * 2048 + ncol] = (unsigned short)f2bf(acc[mt][nt][r] + bs);
      }
    }
  }
}

// ---- O-proj GEMM: 128x64 tile, BK=64; f32 out, +63 row shift, +residual ----
__launch_bounds__(256, 2)
__global__ void cca_gemmO_k(const unsigned short* __restrict__ A,   // Ob bf16
                            const unsigned short* __restrict__ Bt,  // WoT bf16
                            const float* __restrict__ bias,
                            const float* __restrict__ resid,
                            float* __restrict__ out) {
  __shared__ unsigned short Ash[128 * 64];
  __shared__ unsigned short Bsh[64 * 64];
  int tM = blockIdx.x * 128, tN = blockIdx.y * 64;
  int t = threadIdx.x, lane = t & 63, wv = t >> 6;
  int wm = wv >> 1, wn = wv & 1;
  int l15 = lane & 15, quad = lane >> 4;
  int arow = lane >> 3, achk = lane & 7;
  int gchk = achk ^ arow;
  floatx4 acc[4][2];
#pragma unroll
  for (int i = 0; i < 4; ++i)
#pragma unroll
    for (int j = 0; j < 2; ++j) acc[i][j] = zero4();

  for (int k0 = 0; k0 < 1024; k0 += 64) {
    __syncthreads();
#pragma unroll
    for (int ii = 0; ii < 4; ++ii) {
      int seg = ii * 4 + wv;
      int row = seg * 8 + arow;
      gl2lds16(A + (size_t)(tM + row) * 1024 + k0 + gchk * 8, Ash + seg * 512);
    }
#pragma unroll
    for (int ii = 0; ii < 2; ++ii) {
      int seg = ii * 4 + wv;                 // 0..7, 8 rows each
      int row = seg * 8 + arow;
      gl2lds16(Bt + (size_t)(tN + row) * 1024 + k0 + gchk * 8, Bsh + seg * 512);
    }
    __syncthreads();
#pragma unroll
    for (int hseg = 0; hseg < 2; ++hseg) {
      int u = (hseg << 2) | quad;
      bf16x8 af[4], bfv[2];
#pragma unroll
      for (int mt = 0; mt < 4; ++mt) {
        int r = wm * 64 + mt * 16 + l15;
        af[mt] = *(const bf16x8*)&Ash[r * 64 + ((u ^ (l15 & 7)) << 3)];
      }
#pragma unroll
      for (int nt = 0; nt < 2; ++nt) {
        int r = wn * 32 + nt * 16 + l15;
        bfv[nt] = *(const bf16x8*)&Bsh[r * 64 + ((u ^ (l15 & 7)) << 3)];
      }
#pragma unroll
      for (int mt = 0; mt < 4; ++mt)
#pragma unroll
        for (int nt = 0; nt < 2; ++nt)
          acc[mt][nt] = __builtin_amdgcn_mfma_f32_16x16x32_bf16(af[mt], bfv[nt], acc[mt][nt], 0, 0, 0);
    }
  }

#pragma unroll
  for (int mt = 0; mt < 4; ++mt) {
    int mrow = tM + wm * 64 + mt * 16 + quad * 4;
#pragma unroll
    for (int nt = 0; nt < 2; ++nt) {
      int ncol = tN + wn * 32 + nt * 16 + l15;
      float bs = bias[ncol];
#pragma unroll
      for (int r = 0; r < 4; ++r) {
        int m = mrow + r;
        int p = m & 1023;
        if (p < 961) {
          size_t o = (size_t)(m + 63) * 1024 + (size_t)ncol;
          out[o] = acc[mt][nt][r] + bs + resid[o];
        }
      }
    }
  }
}

// ---------------- attention: one block per (b, c, head), 2 blocks/CU --------
__launch_bounds__(256, 2)
__global__ void cca_attn_k(const unsigned short* __restrict__ Q,   // [4096][1024]
                           const unsigned short* __restrict__ KV,  // K cols + VT region
                           unsigned short* __restrict__ O) {       // [4096][1024]
  __shared__ unsigned short smemA[64 * 64 + 256 * 64];
  __shared__ unsigned short VTlds[64 * 256];
  unsigned short* Qsh = smemA;
  unsigned short* Ksh = smemA + 64 * 64;
  unsigned short* Psh = smemA;                // alias (post-barrier)
  int bch = blockIdx.x;
  int hh = bch & 15, c = (bch >> 4) & 15, b = bch >> 8;
  int t = threadIdx.x, lane = t & 63, wv = t >> 6;
  int l15 = lane & 15, quad = lane >> 4;
  size_t qbase = (size_t)b * 1024 + (size_t)c * 64;
  size_t kvbase = (size_t)b * 4096 + (size_t)c * 256;
  int hoff = hh * 64;

  {
    int rowi = lane >> 3, chk = lane & 7;
#pragma unroll
    for (int ii = 0; ii < 2; ++ii) {
      int seg = wv + ii * 4;
      int row = seg * 8 + rowi;
      gl2lds16(Q + (qbase + row) * 1024 + hoff + chk * 8, Qsh + seg * 512);
    }
#pragma unroll
    for (int ii = 0; ii < 8; ++ii) {
      int seg = wv + ii * 4;
      int row = seg * 8 + rowi;
      gl2lds16(KV + (kvbase + row) * 2048 + hoff + chk * 8, Ksh + seg * 512);
    }
    // VT: logical idx i -> KVb[chunk*524288 + (hh*16+(i>>10))*2048 + 1024 + (i&1023)]
    const unsigned short* vbase = KV + (size_t)(b * 16 + c) * 524288 + 1024;
#pragma unroll
    for (int ii = 0; ii < 8; ++ii) {
      int seg = wv + ii * 4;
      int i = seg * 512 + lane * 8;
      gl2lds16(vbase + (size_t)(hh * 16 + (i >> 10)) * 2048 + (i & 1023),
               VTlds + seg * 512);
    }
  }
  __syncthreads();

  floatx4 st[16];
#pragma unroll
  for (int i = 0; i < 16; ++i) st[i] = zero4();
  bf16x8 a0 = *(const bf16x8*)&Qsh[(wv * 16 + l15) * 64 + quad * 8];
  bf16x8 a1 = *(const bf16x8*)&Qsh[(wv * 16 + l15) * 64 + 32 + quad * 8];
#pragma unroll
  for (int kt = 0; kt < 16; ++kt) {
    bf16x8 b0 = *(const bf16x8*)&Ksh[(kt * 16 + l15) * 64 + quad * 8];
    bf16x8 b1 = *(const bf16x8*)&Ksh[(kt * 16 + l15) * 64 + 32 + quad * 8];
    st[kt] = __builtin_amdgcn_mfma_f32_16x16x32_bf16(a0, b0, st[kt], 0, 0, 0);
    st[kt] = __builtin_amdgcn_mfma_f32_16x16x32_bf16(a1, b1, st[kt], 0, 0, 0);
  }
  __syncthreads();   // Qsh/Ksh dead; Psh may alias

  const float scale = 0.125f;  // 1/sqrt(64)
#pragma unroll
  for (int r = 0; r < 4; ++r) {
    float mx = -1e30f;
#pragma unroll
    for (int kt = 0; kt < 16; ++kt) mx = fmaxf(mx, st[kt][r]);
    mx = fmaxf(mx, __shfl_xor(mx, 1));
    mx = fmaxf(mx, __shfl_xor(mx, 2));
    mx = fmaxf(mx, __shfl_xor(mx, 4));
    mx = fmaxf(mx, __shfl_xor(mx, 8));
    float sum = 0.f;
#pragma unroll
    for (int kt = 0; kt < 16; ++kt) {
      float e = __expf((st[kt][r] - mx) * scale);
      st[kt][r] = e;
      sum += e;
    }
    sum += __shfl_xor(sum, 1);
    sum += __shfl_xor(sum, 2);
    sum += __shfl_xor(sum, 4);
    sum += __shfl_xor(sum, 8);
    float inv = 1.0f / sum;
    int prow = wv * 16 + quad * 4 + r;
#pragma unroll
    for (int kt = 0; kt < 16; ++kt)
      Psh[prow * 264 + kt * 16 + l15] = (unsigned short)f2bf(st[kt][r] * inv);
  }

  floatx4 ot[4];
#pragma unroll
  for (int nt = 0; nt < 4; ++nt) ot[nt] = zero4();
#pragma unroll
  for (int kt2 = 0; kt2 < 8; ++kt2) {
    bf16x8 ap = *(const bf16x8*)&Psh[(wv * 16 + l15) * 264 + kt2 * 32 + quad * 8];
#pragma unroll
    for (int nt = 0; nt < 4; ++nt) {
      int vrow = nt * 16 + l15;
      int u = kt2 * 4 + quad;
      bf16x8 bv8 = *(const bf16x8*)&VTlds[vrow * 256 + ((u ^ (vrow & 7)) << 3)];
      ot[nt] = __builtin_amdgcn_mfma_f32_16x16x32_bf16(ap, bv8, ot[nt], 0, 0, 0);
    }
  }
#pragma unroll
  for (int nt = 0; nt < 4; ++nt) {
#pragma unroll
    for (int r = 0; r < 4; ++r) {
      int i = wv * 16 + quad * 4 + r;
      int dcol = hoff + nt * 16 + l15;
      O[(qbase + i) * 1024 + dcol] = (unsigned short)f2bf(ot[nt][r]);
    }
  }
}

extern "C" void kernel_launch(void* const* d_in, const int* in_sizes, int n_in,
                              void* d_out, int out_size, void* d_ws, size_t ws_size,
                              hipStream_t stream) {
  const float* h  = (const float*)d_in[0];
  const float* e  = (const float*)d_in[1];
  const float* g  = (const float*)d_in[2];
  const float* Wq = (const float*)d_in[3];
  const float* bq = (const float*)d_in[4];
  const float* Wk = (const float*)d_in[5];
  const float* bk = (const float*)d_in[6];
  const float* Wv = (const float*)d_in[7];
  const float* bv = (const float*)d_in[8];
  const float* Wo = (const float*)d_in[9];
  const float* bo = (const float*)d_in[10];
  float* out = (float*)d_out;

  unsigned short* ws   = (unsigned short*)d_ws;
  unsigned short* hn   = ws;                                   // 4096*1024
  unsigned short* WqT  = hn   + (size_t)4096 * 1024;           // 1024*1024
  unsigned short* WkvT = WqT  + (size_t)1024 * 1024;           // 2048*1024
  unsigned short* WoT  = WkvT + (size_t)2048 * 1024;           // 1024*1024
  unsigned short* Qb   = WoT  + (size_t)1024 * 1024;           // 4096*1024
  unsigned short* KVb  = Qb   + (size_t)4096 * 1024;           // 16384*2048
  unsigned short* Ob   = KVb  + (size_t)16384 * 2048;          // 4096*1024
  unsigned short* eb   = Ob   + (size_t)4096 * 1024;           // 16384*1024

  cca_prep_k<<<21756, 256, 0, stream>>>(
      Wq, Wk, Wv, Wo, WqT, WkvT, WkvT + (size_t)1024 * 1024, WoT,
      e, eb, h, g, hn, out);

  cca_gemmQKV_k<<<2304, 256, 0, stream>>>(eb, WkvT, bk, bv, KVb,
                                          hn, WqT, bq, Qb);

  cca_attn_k<<<1024, 256, 0, stream>>>(Qb, KVb, Ob);

  cca_gemmO_k<<<dim3(32, 16), 256, 0, stream>>>(Ob, WoT, bo, h, out);
}

// Round 7
// 274.300 us; speedup vs baseline: 1.0245x; 1.0245x over previous
//
#include <hip/hip_runtime.h>
#include <stdint.h>

#define DEV __device__ __forceinline__

typedef __attribute__((ext_vector_type(8))) __bf16 bf16x8;
typedef __attribute__((ext_vector_type(4))) float floatx4;

DEV unsigned int f2bf(float f) {
  union { float f; unsigned int i; } x; x.f = f;
  unsigned int r = x.i + 0x7FFFu + ((x.i >> 16) & 1u);
  return r >> 16;
}
DEV void gl2lds16(const unsigned short* g, unsigned short* l) {
  __builtin_amdgcn_global_load_lds(
      (const __attribute__((address_space(1))) unsigned int*)g,
      (__attribute__((address_space(3))) unsigned int*)l, 16, 0, 0);
}
DEV floatx4 zero4() { floatx4 z; z[0]=0.f; z[1]=0.f; z[2]=0.f; z[3]=0.f; return z; }

// ---- merged prep: [0,1024) weight transposes; [1024,17408) e f32->bf16;
//      [17408,21504) rmsnorm; [21504,21756) head-row copy ---------------------
__global__ void cca_prep_k(const float* __restrict__ W0, const float* __restrict__ W1,
                           const float* __restrict__ W2, const float* __restrict__ W3,
                           unsigned short* __restrict__ D0, unsigned short* __restrict__ D1,
                           unsigned short* __restrict__ D2, unsigned short* __restrict__ D3,
                           const float* __restrict__ e, unsigned short* __restrict__ eb,
                           const float* __restrict__ h, const float* __restrict__ g,
                           unsigned short* __restrict__ hn, float* __restrict__ out) {
  __shared__ float tile[64][65];
  int blk = blockIdx.x;
  int t = threadIdx.x;
  if (blk < 1024) {                       // weight transpose, 64x64 tile
    const float* W; unsigned short* Wt;
    switch (blk >> 8) {
      case 0: W = W0; Wt = D0; break;
      case 1: W = W1; Wt = D1; break;
      case 2: W = W2; Wt = D2; break;
      default: W = W3; Wt = D3; break;
    }
    int k0 = (blk & 15) * 64, n0 = ((blk >> 4) & 15) * 64;
    int c = t & 63, r4 = t >> 6;
#pragma unroll
    for (int it = 0; it < 16; ++it) {
      int r = it * 4 + r4;
      tile[r][c] = W[(size_t)(k0 + r) * 1024 + n0 + c];
    }
    __syncthreads();
#pragma unroll
    for (int it = 0; it < 16; ++it) {
      int r = it * 4 + r4;
      Wt[(size_t)(n0 + r) * 1024 + k0 + c] = (unsigned short)f2bf(tile[c][r]);
    }
    return;
  }
  if (blk < 17408) {                      // e f32 -> bf16, 1024 elems/block
    int i = (blk - 1024) * 256 + t;
    float4 v = ((const float4*)e)[i];
    uint2 o;
    o.x = f2bf(v.x) | (f2bf(v.y) << 16);
    o.y = f2bf(v.z) | (f2bf(v.w) << 16);
    ((uint2*)eb)[i] = o;
    return;
  }
  if (blk < 21504) {                      // rmsnorm row
    int row = blk - 17408;                // 0..4095
    int b = row >> 10, p = row & 1023;
    unsigned short* dst = hn + (size_t)row * 1024;
    if (p >= 961) {
      uint2 z; z.x = 0u; z.y = 0u;
      ((uint2*)dst)[t] = z;
      return;
    }
    const float* src = h + ((size_t)(b << 10) + p + 63) * 1024;
    float4 v = ((const float4*)src)[t];
    float ss = v.x*v.x + v.y*v.y + v.z*v.z + v.w*v.w;
#pragma unroll
    for (int m = 32; m > 0; m >>= 1) ss += __shfl_down(ss, m);
    __shared__ float wsum[4];
    int lane = t & 63, wv = t >> 6;
    if (lane == 0) wsum[wv] = ss;
    __syncthreads();
    float tot = wsum[0] + wsum[1] + wsum[2] + wsum[3];
    float r = rsqrtf(tot * (1.0f / 1024.0f) + 1e-8f);
    float4 gv = ((const float4*)g)[t];
    uint2 outp;
    outp.x = f2bf(v.x * gv.x * r) | (f2bf(v.y * gv.y * r) << 16);
    outp.y = f2bf(v.z * gv.z * r) | (f2bf(v.w * gv.w * r) << 16);
    ((uint2*)dst)[t] = outp;
    return;
  }
  {                                        // head copy, one float4/thread
    int idx = (blk - 21504) * 256 + t;
    const int n4 = 4 * 63 * 1024 / 4;      // 64512
    if (idx < n4) {
      int e4 = idx * 4;
      int b = e4 / (63 * 1024);
      int r = e4 - b * (63 * 1024);
      size_t off = (size_t)b * 1024 * 1024 + (size_t)r;
      *(float4*)(out + off) = *(const float4*)(h + off);
    }
  }
}

// ---- merged QKV GEMM, XCD-aware swizzle, fused LDS-staged VT epilogue ------
// KV blocks [0,2048): x=blk&7 (XCD), s=blk>>3, mblk=x*16+(s&15), n=s>>4.
//   Each XCD gets a contiguous 16-mblk A stripe (4 MB = its L2) x all 16 n.
//   n<8 -> K half (KVb cols [0,1024)); n>=8 -> V half stored transposed+
//   swizzled into KVb's V region: VT elem i(=d*256+((u^(d&7))<<3)+(key&7))
//   of (chunk,hh) lives at KVb[chunk*524288 + (hh*16+(i>>10))*2048 + 1024
//   + (i&1023)].
// Q blocks [2048,2304): x=q&7, s=q>>3, mblk=x*4+(s&3), n=s>>2 -> Qb.
__launch_bounds__(256, 2)
__global__ void cca_gemmQKV_k(const unsigned short* __restrict__ eb,
                              const unsigned short* __restrict__ WkvT,
                              const float* __restrict__ bk,
                              const float* __restrict__ bv,
                              unsigned short* __restrict__ KVb,
                              const unsigned short* __restrict__ hn,
                              const unsigned short* __restrict__ WqT,
                              const float* __restrict__ bq,
                              unsigned short* __restrict__ Qb) {
  __shared__ unsigned short smem[128 * 64 * 2];   // Ash | Bsh, reused as VTsh
  unsigned short* Ash = smem;
  unsigned short* Bsh = smem + 128 * 64;
  int blk = blockIdx.x;
  const unsigned short *A, *Bt;
  int tM, tN;
  bool isQ = (blk >= 2048), isV = false;
  if (!isQ) {
    int x = blk & 7, s = blk >> 3;
    int mblk = x * 16 + (s & 15), n = s >> 4;
    tM = mblk * 128; tN = n * 128; isV = (n >= 8);
    A = eb; Bt = WkvT;
  } else {
    int q = blk - 2048;
    int x = q & 7, s = q >> 3;
    int mblk = x * 4 + (s & 3), n = s >> 2;
    tM = mblk * 128; tN = n * 128;
    A = hn; Bt = WqT;
  }
  int t = threadIdx.x, lane = t & 63, wv = t >> 6;
  int wm = wv >> 1, wn = wv & 1;
  int l15 = lane & 15, quad = lane >> 4;
  int arow = lane >> 3, achk = lane & 7;     // staging: 8 lanes / 128B row
  int gchk = achk ^ arow;                    // 3-bit XOR swizzled source unit
  floatx4 acc[4][4];
#pragma unroll
  for (int i = 0; i < 4; ++i)
#pragma unroll
    for (int j = 0; j < 4; ++j) acc[i][j] = zero4();

  for (int k0 = 0; k0 < 1024; k0 += 64) {
    __syncthreads();
#pragma unroll
    for (int ii = 0; ii < 4; ++ii) {
      int seg = ii * 4 + wv;                 // 0..15, 8 rows each
      int row = seg * 8 + arow;
      gl2lds16(A + (size_t)(tM + row) * 1024 + k0 + gchk * 8, Ash + seg * 512);
      gl2lds16(Bt + (size_t)(tN + row) * 1024 + k0 + gchk * 8, Bsh + seg * 512);
    }
    __syncthreads();
#pragma unroll
    for (int hseg = 0; hseg < 2; ++hseg) {
      int u = (hseg << 2) | quad;
      bf16x8 af[4], bfv[4];
#pragma unroll
      for (int mt = 0; mt < 4; ++mt) {
        int r = wm * 64 + mt * 16 + l15;
        af[mt] = *(const bf16x8*)&Ash[r * 64 + ((u ^ (l15 & 7)) << 3)];
      }
#pragma unroll
      for (int nt = 0; nt < 4; ++nt) {
        int r = wn * 64 + nt * 16 + l15;
        bfv[nt] = *(const bf16x8*)&Bsh[r * 64 + ((u ^ (l15 & 7)) << 3)];
      }
#pragma unroll
      for (int mt = 0; mt < 4; ++mt)
#pragma unroll
        for (int nt = 0; nt < 4; ++nt)
          acc[mt][nt] = __builtin_amdgcn_mfma_f32_16x16x32_bf16(af[mt], bfv[nt], acc[mt][nt], 0, 0, 0);
    }
  }

  if (isV) {
    // V half: build the 32 KB phys image [hhl(2)][d(64)][128 elems] in LDS,
    // then copy out with fully coalesced uint4 stores.
    int chunk = tM >> 8;                    // b*16+c
    int keybase = tM & 255;                 // 0 or 128
    int hh0 = (tN - 1024) >> 6;             // even head index base
    unsigned short* VTsh = smem;
    __syncthreads();                        // all fragment reads done
#pragma unroll
    for (int mt = 0; mt < 4; ++mt) {
      int kl = wm * 64 + mt * 16 + quad * 4;       // key local 0..127 (+r)
      int ul = kl >> 3;                            // local 16B unit 0..15
      int j0 = kl & 7;                             // 0 or 4
#pragma unroll
      for (int nt = 0; nt < 4; ++nt) {
        int d = nt * 16 + l15;                     // 0..63
        float bs = bv[(tN - 1024) + wn * 64 + d];
        int off = (wn * 64 + d) * 128 + ((ul ^ (d & 7)) << 3) + j0;
        uint2 o;
        o.x = f2bf(acc[mt][nt][0] + bs) | (f2bf(acc[mt][nt][1] + bs) << 16);
        o.y = f2bf(acc[mt][nt][2] + bs) | (f2bf(acc[mt][nt][3] + bs) << 16);
        *(uint2*)&VTsh[off] = o;
      }
    }
    __syncthreads();
    unsigned short* vdst = KVb + (size_t)chunk * 524288 + 1024;
#pragma unroll
    for (int it = 0; it < 8; ++it) {
      int flat = it * 256 + t;               // 0..2047 16B units
      int seg = flat >> 4;                   // 0..127 = hhl*64 + d
      int u16 = flat & 15;
      int hhl = seg >> 6, d = seg & 63;
      int hh = hh0 + hhl;
      size_t dst = (size_t)(hh * 16 + (d >> 2)) * 2048 +
                   (d & 3) * 256 + keybase + u16 * 8;
      *(uint4*)(vdst + dst) = *(const uint4*)&VTsh[seg * 128 + u16 * 8];
    }
    return;
  }
#pragma unroll
  for (int mt = 0; mt < 4; ++mt) {
    int mrow = tM + wm * 64 + mt * 16 + quad * 4;
#pragma unroll
    for (int nt = 0; nt < 4; ++nt) {
      int ncol = tN + wn * 64 + nt * 16 + l15;
      float bs = isQ ? bq[ncol] : bk[ncol];
#pragma unroll
      for (int r = 0; r < 4; ++r) {
        int m = mrow + r;
        if (isQ) Qb[(size_t)m * 1024 + ncol] = (unsigned short)f2bf(acc[mt][nt][r] + bs);
        else     KVb[(size_t)m * 2048 + ncol] = (unsigned short)f2bf(acc[mt][nt][r] + bs);
      }
    }
  }
}

// ---- O-proj GEMM: 128x64 tile, BK=64; f32 out, +63 row shift, +residual ----
__launch_bounds__(256, 2)
__global__ void cca_gemmO_k(const unsigned short* __restrict__ A,   // Ob bf16
                            const unsigned short* __restrict__ Bt,  // WoT bf16
                            const float* __restrict__ bias,
                            const float* __restrict__ resid,
                            float* __restrict__ out) {
  __shared__ unsigned short Ash[128 * 64];
  __shared__ unsigned short Bsh[64 * 64];
  int tM = blockIdx.x * 128, tN = blockIdx.y * 64;
  int t = threadIdx.x, lane = t & 63, wv = t >> 6;
  int wm = wv >> 1, wn = wv & 1;
  int l15 = lane & 15, quad = lane >> 4;
  int arow = lane >> 3, achk = lane & 7;
  int gchk = achk ^ arow;
  floatx4 acc[4][2];
#pragma unroll
  for (int i = 0; i < 4; ++i)
#pragma unroll
    for (int j = 0; j < 2; ++j) acc[i][j] = zero4();

  for (int k0 = 0; k0 < 1024; k0 += 64) {
    __syncthreads();
#pragma unroll
    for (int ii = 0; ii < 4; ++ii) {
      int seg = ii * 4 + wv;
      int row = seg * 8 + arow;
      gl2lds16(A + (size_t)(tM + row) * 1024 + k0 + gchk * 8, Ash + seg * 512);
    }
#pragma unroll
    for (int ii = 0; ii < 2; ++ii) {
      int seg = ii * 4 + wv;                 // 0..7, 8 rows each
      int row = seg * 8 + arow;
      gl2lds16(Bt + (size_t)(tN + row) * 1024 + k0 + gchk * 8, Bsh + seg * 512);
    }
    __syncthreads();
#pragma unroll
    for (int hseg = 0; hseg < 2; ++hseg) {
      int u = (hseg << 2) | quad;
      bf16x8 af[4], bfv[2];
#pragma unroll
      for (int mt = 0; mt < 4; ++mt) {
        int r = wm * 64 + mt * 16 + l15;
        af[mt] = *(const bf16x8*)&Ash[r * 64 + ((u ^ (l15 & 7)) << 3)];
      }
#pragma unroll
      for (int nt = 0; nt < 2; ++nt) {
        int r = wn * 32 + nt * 16 + l15;
        bfv[nt] = *(const bf16x8*)&Bsh[r * 64 + ((u ^ (l15 & 7)) << 3)];
      }
#pragma unroll
      for (int mt = 0; mt < 4; ++mt)
#pragma unroll
        for (int nt = 0; nt < 2; ++nt)
          acc[mt][nt] = __builtin_amdgcn_mfma_f32_16x16x32_bf16(af[mt], bfv[nt], acc[mt][nt], 0, 0, 0);
    }
  }

#pragma unroll
  for (int mt = 0; mt < 4; ++mt) {
    int mrow = tM + wm * 64 + mt * 16 + quad * 4;
#pragma unroll
    for (int nt = 0; nt < 2; ++nt) {
      int ncol = tN + wn * 32 + nt * 16 + l15;
      float bs = bias[ncol];
#pragma unroll
      for (int r = 0; r < 4; ++r) {
        int m = mrow + r;
        int p = m & 1023;
        if (p < 961) {
          size_t o = (size_t)(m + 63) * 1024 + (size_t)ncol;
          out[o] = acc[mt][nt][r] + bs + resid[o];
        }
      }
    }
  }
}

// ---------------- attention: one block per (b, c, head), 2 blocks/CU --------
__launch_bounds__(256, 2)
__global__ void cca_attn_k(const unsigned short* __restrict__ Q,   // [4096][1024]
                           const unsigned short* __restrict__ KV,  // K cols + VT region
                           unsigned short* __restrict__ O) {       // [4096][1024]
  __shared__ unsigned short smemA[64 * 64 + 256 * 64];
  __shared__ unsigned short VTlds[64 * 256];
  unsigned short* Qsh = smemA;
  unsigned short* Ksh = smemA + 64 * 64;
  unsigned short* Psh = smemA;                // alias (post-barrier)
  int bch = blockIdx.x;
  int hh = bch & 15, c = (bch >> 4) & 15, b = bch >> 8;
  int t = threadIdx.x, lane = t & 63, wv = t >> 6;
  int l15 = lane & 15, quad = lane >> 4;
  size_t qbase = (size_t)b * 1024 + (size_t)c * 64;
  size_t kvbase = (size_t)b * 4096 + (size_t)c * 256;
  int hoff = hh * 64;

  {
    int rowi = lane >> 3, chk = lane & 7;
#pragma unroll
    for (int ii = 0; ii < 2; ++ii) {
      int seg = wv + ii * 4;
      int row = seg * 8 + rowi;
      gl2lds16(Q + (qbase + row) * 1024 + hoff + chk * 8, Qsh + seg * 512);
    }
#pragma unroll
    for (int ii = 0; ii < 8; ++ii) {
      int seg = wv + ii * 4;
      int row = seg * 8 + rowi;
      gl2lds16(KV + (kvbase + row) * 2048 + hoff + chk * 8, Ksh + seg * 512);
    }
    // VT: logical idx i -> KVb[chunk*524288 + (hh*16+(i>>10))*2048 + 1024 + (i&1023)]
    const unsigned short* vbase = KV + (size_t)(b * 16 + c) * 524288 + 1024;
#pragma unroll
    for (int ii = 0; ii < 8; ++ii) {
      int seg = wv + ii * 4;
      int i = seg * 512 + lane * 8;
      gl2lds16(vbase + (size_t)(hh * 16 + (i >> 10)) * 2048 + (i & 1023),
               VTlds + seg * 512);
    }
  }
  __syncthreads();

  floatx4 st[16];
#pragma unroll
  for (int i = 0; i < 16; ++i) st[i] = zero4();
  bf16x8 a0 = *(const bf16x8*)&Qsh[(wv * 16 + l15) * 64 + quad * 8];
  bf16x8 a1 = *(const bf16x8*)&Qsh[(wv * 16 + l15) * 64 + 32 + quad * 8];
#pragma unroll
  for (int kt = 0; kt < 16; ++kt) {
    bf16x8 b0 = *(const bf16x8*)&Ksh[(kt * 16 + l15) * 64 + quad * 8];
    bf16x8 b1 = *(const bf16x8*)&Ksh[(kt * 16 + l15) * 64 + 32 + quad * 8];
    st[kt] = __builtin_amdgcn_mfma_f32_16x16x32_bf16(a0, b0, st[kt], 0, 0, 0);
    st[kt] = __builtin_amdgcn_mfma_f32_16x16x32_bf16(a1, b1, st[kt], 0, 0, 0);
  }
  __syncthreads();   // Qsh/Ksh dead; Psh may alias

  const float scale = 0.125f;  // 1/sqrt(64)
#pragma unroll
  for (int r = 0; r < 4; ++r) {
    float mx = -1e30f;
#pragma unroll
    for (int kt = 0; kt < 16; ++kt) mx = fmaxf(mx, st[kt][r]);
    mx = fmaxf(mx, __shfl_xor(mx, 1));
    mx = fmaxf(mx, __shfl_xor(mx, 2));
    mx = fmaxf(mx, __shfl_xor(mx, 4));
    mx = fmaxf(mx, __shfl_xor(mx, 8));
    float sum = 0.f;
#pragma unroll
    for (int kt = 0; kt < 16; ++kt) {
      float e = __expf((st[kt][r] - mx) * scale);
      st[kt][r] = e;
      sum += e;
    }
    sum += __shfl_xor(sum, 1);
    sum += __shfl_xor(sum, 2);
    sum += __shfl_xor(sum, 4);
    sum += __shfl_xor(sum, 8);
    float inv = 1.0f / sum;
    int prow = wv * 16 + quad * 4 + r;
#pragma unroll
    for (int kt = 0; kt < 16; ++kt)
      Psh[prow * 264 + kt * 16 + l15] = (unsigned short)f2bf(st[kt][r] * inv);
  }

  floatx4 ot[4];
#pragma unroll
  for (int nt = 0; nt < 4; ++nt) ot[nt] = zero4();
#pragma unroll
  for (int kt2 = 0; kt2 < 8; ++kt2) {
    bf16x8 ap = *(const bf16x8*)&Psh[(wv * 16 + l15) * 264 + kt2 * 32 + quad * 8];
#pragma unroll
    for (int nt = 0; nt < 4; ++nt) {
      int vrow = nt * 16 + l15;
      int u = kt2 * 4 + quad;
      bf16x8 bv8 = *(const bf16x8*)&VTlds[vrow * 256 + ((u ^ (vrow & 7)) << 3)];
      ot[nt] = __builtin_amdgcn_mfma_f32_16x16x32_bf16(ap, bv8, ot[nt], 0, 0, 0);
    }
  }
#pragma unroll
  for (int nt = 0; nt < 4; ++nt) {
#pragma unroll
    for (int r = 0; r < 4; ++r) {
      int i = wv * 16 + quad * 4 + r;
      int dcol = hoff + nt * 16 + l15;
      O[(qbase + i) * 1024 + dcol] = (unsigned short)f2bf(ot[nt][r]);
    }
  }
}

extern "C" void kernel_launch(void* const* d_in, const int* in_sizes, int n_in,
                              void* d_out, int out_size, void* d_ws, size_t ws_size,
                              hipStream_t stream) {
  const float* h  = (const float*)d_in[0];
  const float* e  = (const float*)d_in[1];
  const float* g  = (const float*)d_in[2];
  const float* Wq = (const float*)d_in[3];
  const float* bq = (const float*)d_in[4];
  const float* Wk = (const float*)d_in[5];
  const float* bk = (const float*)d_in[6];
  const float* Wv = (const float*)d_in[7];
  const float* bv = (const float*)d_in[8];
  const float* Wo = (const float*)d_in[9];
  const float* bo = (const float*)d_in[10];
  float* out = (float*)d_out;

  unsigned short* ws   = (unsigned short*)d_ws;
  unsigned short* hn   = ws;                                   // 4096*1024
  unsigned short* WqT  = hn   + (size_t)4096 * 1024;           // 1024*1024
  unsigned short* WkvT = WqT  + (size_t)1024 * 1024;           // 2048*1024
  unsigned short* WoT  = WkvT + (size_t)2048 * 1024;           // 1024*1024
  unsigned short* Qb   = WoT  + (size_t)1024 * 1024;           // 4096*1024
  unsigned short* KVb  = Qb   + (size_t)4096 * 1024;           // 16384*2048
  unsigned short* Ob   = KVb  + (size_t)16384 * 2048;          // 4096*1024
  unsigned short* eb   = Ob   + (size_t)4096 * 1024;           // 16384*1024

  cca_prep_k<<<21756, 256, 0, stream>>>(
      Wq, Wk, Wv, Wo, WqT, WkvT, WkvT + (size_t)1024 * 1024, WoT,
      e, eb, h, g, hn, out);

  cca_gemmQKV_k<<<2304, 256, 0, stream>>>(eb, WkvT, bk, bv, KVb,
                                          hn, WqT, bq, Qb);

  cca_attn_k<<<1024, 256, 0, stream>>>(Qb, KVb, Ob);

  cca_gemmO_k<<<dim3(32, 16), 256, 0, stream>>>(Ob, WoT, bo, h, out);
}

// Round 8
// 271.343 us; speedup vs baseline: 1.0357x; 1.0109x over previous
//
#include <hip/hip_runtime.h>
#include <stdint.h>

#define DEV __device__ __forceinline__

typedef __attribute__((ext_vector_type(8))) __bf16 bf16x8;
typedef __attribute__((ext_vector_type(4))) float floatx4;

DEV unsigned int f2bf(float f) {
  union { float f; unsigned int i; } x; x.f = f;
  unsigned int r = x.i + 0x7FFFu + ((x.i >> 16) & 1u);
  return r >> 16;
}
DEV void gl2lds16(const unsigned short* g, unsigned short* l) {
  __builtin_amdgcn_global_load_lds(
      (const __attribute__((address_space(1))) unsigned int*)g,
      (__attribute__((address_space(3))) unsigned int*)l, 16, 0, 0);
}
DEV floatx4 zero4() { floatx4 z; z[0]=0.f; z[1]=0.f; z[2]=0.f; z[3]=0.f; return z; }

// ---- merged prep: [0,1024) weight transposes; [1024,17408) e f32->bf16;
//      [17408,21504) rmsnorm; [21504,21756) head-row copy ---------------------
__global__ void cca_prep_k(const float* __restrict__ W0, const float* __restrict__ W1,
                           const float* __restrict__ W2, const float* __restrict__ W3,
                           unsigned short* __restrict__ D0, unsigned short* __restrict__ D1,
                           unsigned short* __restrict__ D2, unsigned short* __restrict__ D3,
                           const float* __restrict__ e, unsigned short* __restrict__ eb,
                           const float* __restrict__ h, const float* __restrict__ g,
                           unsigned short* __restrict__ hn, float* __restrict__ out) {
  __shared__ float tile[64][65];
  int blk = blockIdx.x;
  int t = threadIdx.x;
  if (blk < 1024) {                       // weight transpose, 64x64 tile
    const float* W; unsigned short* Wt;
    switch (blk >> 8) {
      case 0: W = W0; Wt = D0; break;
      case 1: W = W1; Wt = D1; break;
      case 2: W = W2; Wt = D2; break;
      default: W = W3; Wt = D3; break;
    }
    int k0 = (blk & 15) * 64, n0 = ((blk >> 4) & 15) * 64;
    int c = t & 63, r4 = t >> 6;
#pragma unroll
    for (int it = 0; it < 16; ++it) {
      int r = it * 4 + r4;
      tile[r][c] = W[(size_t)(k0 + r) * 1024 + n0 + c];
    }
    __syncthreads();
#pragma unroll
    for (int it = 0; it < 16; ++it) {
      int r = it * 4 + r4;
      Wt[(size_t)(n0 + r) * 1024 + k0 + c] = (unsigned short)f2bf(tile[c][r]);
    }
    return;
  }
  if (blk < 17408) {                      // e f32 -> bf16, 1024 elems/block
    int i = (blk - 1024) * 256 + t;
    float4 v = ((const float4*)e)[i];
    uint2 o;
    o.x = f2bf(v.x) | (f2bf(v.y) << 16);
    o.y = f2bf(v.z) | (f2bf(v.w) << 16);
    ((uint2*)eb)[i] = o;
    return;
  }
  if (blk < 21504) {                      // rmsnorm row
    int row = blk - 17408;                // 0..4095
    int b = row >> 10, p = row & 1023;
    unsigned short* dst = hn + (size_t)row * 1024;
    if (p >= 961) {
      uint2 z; z.x = 0u; z.y = 0u;
      ((uint2*)dst)[t] = z;
      return;
    }
    const float* src = h + ((size_t)(b << 10) + p + 63) * 1024;
    float4 v = ((const float4*)src)[t];
    float ss = v.x*v.x + v.y*v.y + v.z*v.z + v.w*v.w;
#pragma unroll
    for (int m = 32; m > 0; m >>= 1) ss += __shfl_down(ss, m);
    __shared__ float wsum[4];
    int lane = t & 63, wv = t >> 6;
    if (lane == 0) wsum[wv] = ss;
    __syncthreads();
    float tot = wsum[0] + wsum[1] + wsum[2] + wsum[3];
    float r = rsqrtf(tot * (1.0f / 1024.0f) + 1e-8f);
    float4 gv = ((const float4*)g)[t];
    uint2 outp;
    outp.x = f2bf(v.x * gv.x * r) | (f2bf(v.y * gv.y * r) << 16);
    outp.y = f2bf(v.z * gv.z * r) | (f2bf(v.w * gv.w * r) << 16);
    ((uint2*)dst)[t] = outp;
    return;
  }
  {                                        // head copy, one float4/thread
    int idx = (blk - 21504) * 256 + t;
    const int n4 = 4 * 63 * 1024 / 4;      // 64512
    if (idx < n4) {
      int e4 = idx * 4;
      int b = e4 / (63 * 1024);
      int r = e4 - b * (63 * 1024);
      size_t off = (size_t)b * 1024 * 1024 + (size_t)r;
      *(float4*)(out + off) = *(const float4*)(h + off);
    }
  }
}

// ---- merged QKV GEMM, XCD-aware swizzle, fused LDS-staged VT epilogue ------
// KV blocks [0,2048): x=blk&7 (XCD), s=blk>>3, mblk=x*16+(s&15), n=s>>4.
//   Each XCD gets a contiguous 16-mblk A stripe (4 MB = its L2) x all 16 n.
//   n<8 -> K half (KVb cols [0,1024)); n>=8 -> V half stored transposed+
//   swizzled into KVb's V region: VT elem i(=d*256+((u^(d&7))<<3)+(key&7))
//   of (chunk,hh) lives at KVb[chunk*524288 + (hh*16+(i>>10))*2048 + 1024
//   + (i&1023)].
// Q blocks [2048,2304): x=q&7, s=q>>3, mblk=x*4+(s&3), n=s>>2 -> Qb.
// launch_bounds(256,4): VGPR=64, LDS=32KB -> 4 blocks/CU; cross-block overlap
// hides each block's barrier drain (m114 model).
__launch_bounds__(256, 4)
__global__ void cca_gemmQKV_k(const unsigned short* __restrict__ eb,
                              const unsigned short* __restrict__ WkvT,
                              const float* __restrict__ bk,
                              const float* __restrict__ bv,
                              unsigned short* __restrict__ KVb,
                              const unsigned short* __restrict__ hn,
                              const unsigned short* __restrict__ WqT,
                              const float* __restrict__ bq,
                              unsigned short* __restrict__ Qb) {
  __shared__ unsigned short smem[128 * 64 * 2];   // Ash | Bsh, reused as VTsh
  unsigned short* Ash = smem;
  unsigned short* Bsh = smem + 128 * 64;
  int blk = blockIdx.x;
  const unsigned short *A, *Bt;
  int tM, tN;
  bool isQ = (blk >= 2048), isV = false;
  if (!isQ) {
    int x = blk & 7, s = blk >> 3;
    int mblk = x * 16 + (s & 15), n = s >> 4;
    tM = mblk * 128; tN = n * 128; isV = (n >= 8);
    A = eb; Bt = WkvT;
  } else {
    int q = blk - 2048;
    int x = q & 7, s = q >> 3;
    int mblk = x * 4 + (s & 3), n = s >> 2;
    tM = mblk * 128; tN = n * 128;
    A = hn; Bt = WqT;
  }
  int t = threadIdx.x, lane = t & 63, wv = t >> 6;
  int wm = wv >> 1, wn = wv & 1;
  int l15 = lane & 15, quad = lane >> 4;
  int arow = lane >> 3, achk = lane & 7;     // staging: 8 lanes / 128B row
  int gchk = achk ^ arow;                    // 3-bit XOR swizzled source unit
  floatx4 acc[4][4];
#pragma unroll
  for (int i = 0; i < 4; ++i)
#pragma unroll
    for (int j = 0; j < 4; ++j) acc[i][j] = zero4();

  for (int k0 = 0; k0 < 1024; k0 += 64) {
    __syncthreads();
#pragma unroll
    for (int ii = 0; ii < 4; ++ii) {
      int seg = ii * 4 + wv;                 // 0..15, 8 rows each
      int row = seg * 8 + arow;
      gl2lds16(A + (size_t)(tM + row) * 1024 + k0 + gchk * 8, Ash + seg * 512);
      gl2lds16(Bt + (size_t)(tN + row) * 1024 + k0 + gchk * 8, Bsh + seg * 512);
    }
    __syncthreads();
#pragma unroll
    for (int hseg = 0; hseg < 2; ++hseg) {
      int u = (hseg << 2) | quad;
      bf16x8 af[4], bfv[4];
#pragma unroll
      for (int mt = 0; mt < 4; ++mt) {
        int r = wm * 64 + mt * 16 + l15;
        af[mt] = *(const bf16x8*)&Ash[r * 64 + ((u ^ (l15 & 7)) << 3)];
      }
#pragma unroll
      for (int nt = 0; nt < 4; ++nt) {
        int r = wn * 64 + nt * 16 + l15;
        bfv[nt] = *(const bf16x8*)&Bsh[r * 64 + ((u ^ (l15 & 7)) << 3)];
      }
#pragma unroll
      for (int mt = 0; mt < 4; ++mt)
#pragma unroll
        for (int nt = 0; nt < 4; ++nt)
          acc[mt][nt] = __builtin_amdgcn_mfma_f32_16x16x32_bf16(af[mt], bfv[nt], acc[mt][nt], 0, 0, 0);
    }
  }

  if (isV) {
    // V half: build the 32 KB phys image [hhl(2)][d(64)][128 elems] in LDS,
    // then copy out with fully coalesced uint4 stores.
    int chunk = tM >> 8;                    // b*16+c
    int keybase = tM & 255;                 // 0 or 128
    int hh0 = (tN - 1024) >> 6;             // even head index base
    unsigned short* VTsh = smem;
    __syncthreads();                        // all fragment reads done
#pragma unroll
    for (int mt = 0; mt < 4; ++mt) {
      int kl = wm * 64 + mt * 16 + quad * 4;       // key local 0..127 (+r)
      int ul = kl >> 3;                            // local 16B unit 0..15
      int j0 = kl & 7;                             // 0 or 4
#pragma unroll
      for (int nt = 0; nt < 4; ++nt) {
        int d = nt * 16 + l15;                     // 0..63
        float bs = bv[(tN - 1024) + wn * 64 + d];
        int off = (wn * 64 + d) * 128 + ((ul ^ (d & 7)) << 3) + j0;
        uint2 o;
        o.x = f2bf(acc[mt][nt][0] + bs) | (f2bf(acc[mt][nt][1] + bs) << 16);
        o.y = f2bf(acc[mt][nt][2] + bs) | (f2bf(acc[mt][nt][3] + bs) << 16);
        *(uint2*)&VTsh[off] = o;
      }
    }
    __syncthreads();
    unsigned short* vdst = KVb + (size_t)chunk * 524288 + 1024;
#pragma unroll
    for (int it = 0; it < 8; ++it) {
      int flat = it * 256 + t;               // 0..2047 16B units
      int seg = flat >> 4;                   // 0..127 = hhl*64 + d
      int u16 = flat & 15;
      int hhl = seg >> 6, d = seg & 63;
      int hh = hh0 + hhl;
      size_t dst = (size_t)(hh * 16 + (d >> 2)) * 2048 +
                   (d & 3) * 256 + keybase + u16 * 8;
      *(uint4*)(vdst + dst) = *(const uint4*)&VTsh[seg * 128 + u16 * 8];
    }
    return;
  }
#pragma unroll
  for (int mt = 0; mt < 4; ++mt) {
    int mrow = tM + wm * 64 + mt * 16 + quad * 4;
#pragma unroll
    for (int nt = 0; nt < 4; ++nt) {
      int ncol = tN + wn * 64 + nt * 16 + l15;
      float bs = isQ ? bq[ncol] : bk[ncol];
#pragma unroll
      for (int r = 0; r < 4; ++r) {
        int m = mrow + r;
        if (isQ) Qb[(size_t)m * 1024 + ncol] = (unsigned short)f2bf(acc[mt][nt][r] + bs);
        else     KVb[(size_t)m * 2048 + ncol] = (unsigned short)f2bf(acc[mt][nt][r] + bs);
      }
    }
  }
}

// ---- O-proj GEMM: 128x64 tile, BK=64; f32 out, +63 row shift, +residual ----
// launch_bounds(256,4): 24KB LDS -> 4 blocks/CU
__launch_bounds__(256, 4)
__global__ void cca_gemmO_k(const unsigned short* __restrict__ A,   // Ob bf16
                            const unsigned short* __restrict__ Bt,  // WoT bf16
                            const float* __restrict__ bias,
                            const float* __restrict__ resid,
                            float* __restrict__ out) {
  __shared__ unsigned short Ash[128 * 64];
  __shared__ unsigned short Bsh[64 * 64];
  int tM = blockIdx.x * 128, tN = blockIdx.y * 64;
  int t = threadIdx.x, lane = t & 63, wv = t >> 6;
  int wm = wv >> 1, wn = wv & 1;
  int l15 = lane & 15, quad = lane >> 4;
  int arow = lane >> 3, achk = lane & 7;
  int gchk = achk ^ arow;
  floatx4 acc[4][2];
#pragma unroll
  for (int i = 0; i < 4; ++i)
#pragma unroll
    for (int j = 0; j < 2; ++j) acc[i][j] = zero4();

  for (int k0 = 0; k0 < 1024; k0 += 64) {
    __syncthreads();
#pragma unroll
    for (int ii = 0; ii < 4; ++ii) {
      int seg = ii * 4 + wv;
      int row = seg * 8 + arow;
      gl2lds16(A + (size_t)(tM + row) * 1024 + k0 + gchk * 8, Ash + seg * 512);
    }
#pragma unroll
    for (int ii = 0; ii < 2; ++ii) {
      int seg = ii * 4 + wv;                 // 0..7, 8 rows each
      int row = seg * 8 + arow;
      gl2lds16(Bt + (size_t)(tN + row) * 1024 + k0 + gchk * 8, Bsh + seg * 512);
    }
    __syncthreads();
#pragma unroll
    for (int hseg = 0; hseg < 2; ++hseg) {
      int u = (hseg << 2) | quad;
      bf16x8 af[4], bfv[2];
#pragma unroll
      for (int mt = 0; mt < 4; ++mt) {
        int r = wm * 64 + mt * 16 + l15;
        af[mt] = *(const bf16x8*)&Ash[r * 64 + ((u ^ (l15 & 7)) << 3)];
      }
#pragma unroll
      for (int nt = 0; nt < 2; ++nt) {
        int r = wn * 32 + nt * 16 + l15;
        bfv[nt] = *(const bf16x8*)&Bsh[r * 64 + ((u ^ (l15 & 7)) << 3)];
      }
#pragma unroll
      for (int mt = 0; mt < 4; ++mt)
#pragma unroll
        for (int nt = 0; nt < 2; ++nt)
          acc[mt][nt] = __builtin_amdgcn_mfma_f32_16x16x32_bf16(af[mt], bfv[nt], acc[mt][nt], 0, 0, 0);
    }
  }

#pragma unroll
  for (int mt = 0; mt < 4; ++mt) {
    int mrow = tM + wm * 64 + mt * 16 + quad * 4;
#pragma unroll
    for (int nt = 0; nt < 2; ++nt) {
      int ncol = tN + wn * 32 + nt * 16 + l15;
      float bs = bias[ncol];
#pragma unroll
      for (int r = 0; r < 4; ++r) {
        int m = mrow + r;
        int p = m & 1023;
        if (p < 961) {
          size_t o = (size_t)(m + 63) * 1024 + (size_t)ncol;
          out[o] = acc[mt][nt][r] + bs + resid[o];
        }
      }
    }
  }
}

// ---------------- attention: one block per (b, c, head), 2 blocks/CU --------
__launch_bounds__(256, 2)
__global__ void cca_attn_k(const unsigned short* __restrict__ Q,   // [4096][1024]
                           const unsigned short* __restrict__ KV,  // K cols + VT region
                           unsigned short* __restrict__ O) {       // [4096][1024]
  __shared__ unsigned short smemA[64 * 64 + 256 * 64];
  __shared__ unsigned short VTlds[64 * 256];
  unsigned short* Qsh = smemA;
  unsigned short* Ksh = smemA + 64 * 64;
  unsigned short* Psh = smemA;                // alias (post-barrier)
  int bch = blockIdx.x;
  int hh = bch & 15, c = (bch >> 4) & 15, b = bch >> 8;
  int t = threadIdx.x, lane = t & 63, wv = t >> 6;
  int l15 = lane & 15, quad = lane >> 4;
  size_t qbase = (size_t)b * 1024 + (size_t)c * 64;
  size_t kvbase = (size_t)b * 4096 + (size_t)c * 256;
  int hoff = hh * 64;

  {
    int rowi = lane >> 3, chk = lane & 7;
#pragma unroll
    for (int ii = 0; ii < 2; ++ii) {
      int seg = wv + ii * 4;
      int row = seg * 8 + rowi;
      gl2lds16(Q + (qbase + row) * 1024 + hoff + chk * 8, Qsh + seg * 512);
    }
#pragma unroll
    for (int ii = 0; ii < 8; ++ii) {
      int seg = wv + ii * 4;
      int row = seg * 8 + rowi;
      gl2lds16(KV + (kvbase + row) * 2048 + hoff + chk * 8, Ksh + seg * 512);
    }
    // VT: logical idx i -> KVb[chunk*524288 + (hh*16+(i>>10))*2048 + 1024 + (i&1023)]
    const unsigned short* vbase = KV + (size_t)(b * 16 + c) * 524288 + 1024;
#pragma unroll
    for (int ii = 0; ii < 8; ++ii) {
      int seg = wv + ii * 4;
      int i = seg * 512 + lane * 8;
      gl2lds16(vbase + (size_t)(hh * 16 + (i >> 10)) * 2048 + (i & 1023),
               VTlds + seg * 512);
    }
  }
  __syncthreads();

  floatx4 st[16];
#pragma unroll
  for (int i = 0; i < 16; ++i) st[i] = zero4();
  bf16x8 a0 = *(const bf16x8*)&Qsh[(wv * 16 + l15) * 64 + quad * 8];
  bf16x8 a1 = *(const bf16x8*)&Qsh[(wv * 16 + l15) * 64 + 32 + quad * 8];
#pragma unroll
  for (int kt = 0; kt < 16; ++kt) {
    bf16x8 b0 = *(const bf16x8*)&Ksh[(kt * 16 + l15) * 64 + quad * 8];
    bf16x8 b1 = *(const bf16x8*)&Ksh[(kt * 16 + l15) * 64 + 32 + quad * 8];
    st[kt] = __builtin_amdgcn_mfma_f32_16x16x32_bf16(a0, b0, st[kt], 0, 0, 0);
    st[kt] = __builtin_amdgcn_mfma_f32_16x16x32_bf16(a1, b1, st[kt], 0, 0, 0);
  }
  __syncthreads();   // Qsh/Ksh dead; Psh may alias

  const float scale = 0.125f;  // 1/sqrt(64)
#pragma unroll
  for (int r = 0; r < 4; ++r) {
    float mx = -1e30f;
#pragma unroll
    for (int kt = 0; kt < 16; ++kt) mx = fmaxf(mx, st[kt][r]);
    mx = fmaxf(mx, __shfl_xor(mx, 1));
    mx = fmaxf(mx, __shfl_xor(mx, 2));
    mx = fmaxf(mx, __shfl_xor(mx, 4));
    mx = fmaxf(mx, __shfl_xor(mx, 8));
    float sum = 0.f;
#pragma unroll
    for (int kt = 0; kt < 16; ++kt) {
      float e = __expf((st[kt][r] - mx) * scale);
      st[kt][r] = e;
      sum += e;
    }
    sum += __shfl_xor(sum, 1);
    sum += __shfl_xor(sum, 2);
    sum += __shfl_xor(sum, 4);
    sum += __shfl_xor(sum, 8);
    float inv = 1.0f / sum;
    int prow = wv * 16 + quad * 4 + r;
#pragma unroll
    for (int kt = 0; kt < 16; ++kt)
      Psh[prow * 264 + kt * 16 + l15] = (unsigned short)f2bf(st[kt][r] * inv);
  }

  floatx4 ot[4];
#pragma unroll
  for (int nt = 0; nt < 4; ++nt) ot[nt] = zero4();
#pragma unroll
  for (int kt2 = 0; kt2 < 8; ++kt2) {
    bf16x8 ap = *(const bf16x8*)&Psh[(wv * 16 + l15) * 264 + kt2 * 32 + quad * 8];
#pragma unroll
    for (int nt = 0; nt < 4; ++nt) {
      int vrow = nt * 16 + l15;
      int u = kt2 * 4 + quad;
      bf16x8 bv8 = *(const bf16x8*)&VTlds[vrow * 256 + ((u ^ (vrow & 7)) << 3)];
      ot[nt] = __builtin_amdgcn_mfma_f32_16x16x32_bf16(ap, bv8, ot[nt], 0, 0, 0);
    }
  }
#pragma unroll
  for (int nt = 0; nt < 4; ++nt) {
#pragma unroll
    for (int r = 0; r < 4; ++r) {
      int i = wv * 16 + quad * 4 + r;
      int dcol = hoff + nt * 16 + l15;
      O[(qbase + i) * 1024 + dcol] = (unsigned short)f2bf(ot[nt][r]);
    }
  }
}

extern "C" void kernel_launch(void* const* d_in, const int* in_sizes, int n_in,
                              void* d_out, int out_size, void* d_ws, size_t ws_size,
                              hipStream_t stream) {
  const float* h  = (const float*)d_in[0];
  const float* e  = (const float*)d_in[1];
  const float* g  = (const float*)d_in[2];
  const float* Wq = (const float*)d_in[3];
  const float* bq = (const float*)d_in[4];
  const float* Wk = (const float*)d_in[5];
  const float* bk = (const float*)d_in[6];
  const float* Wv = (const float*)d_in[7];
  const float* bv = (const float*)d_in[8];
  const float* Wo = (const float*)d_in[9];
  const float* bo = (const float*)d_in[10];
  float* out = (float*)d_out;

  unsigned short* ws   = (unsigned short*)d_ws;
  unsigned short* hn   = ws;                                   // 4096*1024
  unsigned short* WqT  = hn   + (size_t)4096 * 1024;           // 1024*1024
  unsigned short* WkvT = WqT  + (size_t)1024 * 1024;           // 2048*1024
  unsigned short* WoT  = WkvT + (size_t)2048 * 1024;           // 1024*1024
  unsigned short* Qb   = WoT  + (size_t)1024 * 1024;           // 4096*1024
  unsigned short* KVb  = Qb   + (size_t)4096 * 1024;           // 16384*2048
  unsigned short* Ob   = KVb  + (size_t)16384 * 2048;          // 4096*1024
  unsigned short* eb   = Ob   + (size_t)4096 * 1024;           // 16384*1024

  cca_prep_k<<<21756, 256, 0, stream>>>(
      Wq, Wk, Wv, Wo, WqT, WkvT, WkvT + (size_t)1024 * 1024, WoT,
      e, eb, h, g, hn, out);

  cca_gemmQKV_k<<<2304, 256, 0, stream>>>(eb, WkvT, bk, bv, KVb,
                                          hn, WqT, bq, Qb);

  cca_attn_k<<<1024, 256, 0, stream>>>(Qb, KVb, Ob);

  cca_gemmO_k<<<dim3(32, 16), 256, 0, stream>>>(Ob, WoT, bo, h, out);
}